// Round 2
// baseline (823.540 us; speedup 1.0000x reference)
//
#include <hip/hip_runtime.h>
#include <hip/hip_bf16.h>

// CFConv, round 1.
//   out = segment_sum( (x@Wl+bl)[col] * (relu(rbf@W1+b1)@W2+b2), row )
// Changes vs round 0:
//  - node linear now MFMA-based (was 260us of fp32 VALU + redundant Wl staging)
//  - h stored as bf16 (halves gather traffic)
//  - edges counting-sorted by dst row (hist/scan/scatter kernels), edge kernel
//    accumulates per-dst runs in LDS (ds_add_f32) and flushes ~1 global atomic
//    per (distinct dst x channel) per tile: 82M -> ~6.6M global atomics.

#define N_NODES 40000
#define N_EDGES 640000
#define IN_CH 128
#define OUT_CH 128
#define NUM_RBF 64

#define TILE_M 64
#define NTILES (N_EDGES / TILE_M)  // 10000
#define RBF_STR 72                 // ushorts
#define T_STR 136                  // ushorts
#define ACC_STR 132                // floats
#define W1_STR 72
#define W2_STR 136

#define POOL_BYTES (TILE_M * ACC_STR * 4 + TILE_M * RBF_STR * 2)  // 33792+9216=43008

typedef __attribute__((ext_vector_type(8))) short bf16x8;
typedef __attribute__((ext_vector_type(16))) float f32x16;

__device__ __forceinline__ unsigned short f2bf(float f) {
  unsigned u = __float_as_uint(f);
  return (unsigned short)((u + 0x7FFFu + ((u >> 16) & 1u)) >> 16);
}
__device__ __forceinline__ float bf2f(unsigned short s) {
  return __uint_as_float(((unsigned)s) << 16);
}

// ---------------------------------------------------------------------------
// h = bf16(x @ Wl + bl)   MFMA, Wl fragments register-resident per wave
// ---------------------------------------------------------------------------
__global__ __launch_bounds__(256) void node_linear_mfma(
    const float* __restrict__ x, const float* __restrict__ Wl,
    const float* __restrict__ bl, unsigned short* __restrict__ hbf) {
  __shared__ __align__(16) char pool[IN_CH * W2_STR * 2];  // 34816 B
  const int t = threadIdx.x;
  const int lane = t & 63;
  const int l31 = lane & 31;
  const int lhalf = lane >> 5;
  const int wv = t >> 6;

  // stage Wl^T (c-major, k-contig) as bf16
  {
    unsigned short* sWT = (unsigned short*)pool;
    const int k2 = t >> 1;
    const int d0 = (t & 1) * 64;
#pragma unroll
    for (int i = 0; i < 16; ++i) {
      float4 v = *(const float4*)(Wl + k2 * OUT_CH + d0 + 4 * i);
      sWT[(d0 + 4 * i + 0) * W2_STR + k2] = f2bf(v.x);
      sWT[(d0 + 4 * i + 1) * W2_STR + k2] = f2bf(v.y);
      sWT[(d0 + 4 * i + 2) * W2_STR + k2] = f2bf(v.z);
      sWT[(d0 + 4 * i + 3) * W2_STR + k2] = f2bf(v.w);
    }
  }
  __syncthreads();
  const int nbase = wv * 32 + l31;
  bf16x8 BW[8];
  {
    const unsigned short* sWT = (const unsigned short*)pool;
#pragma unroll
    for (int kk = 0; kk < 8; ++kk)
      BW[kk] = *(const bf16x8*)&sWT[nbase * W2_STR + kk * 16 + lhalf * 8];
  }
  const float blv = bl[nbase];
  __syncthreads();

  const int rbase = blockIdx.x * TILE_M;
  unsigned short* sX = (unsigned short*)pool;  // x tile [m][k], stride T_STR
  {
    const int m = t >> 2;
    const int c0 = (t & 3) * 32;
    const float* src = x + (size_t)(rbase + m) * IN_CH + c0;
#pragma unroll
    for (int i = 0; i < 8; ++i) {
      float4 v = *(const float4*)(src + 4 * i);
      ushort4 p;
      p.x = f2bf(v.x); p.y = f2bf(v.y); p.z = f2bf(v.z); p.w = f2bf(v.w);
      *(ushort4*)&sX[m * T_STR + c0 + 4 * i] = p;
    }
  }
  __syncthreads();
#pragma unroll
  for (int mt = 0; mt < 2; ++mt) {
    f32x16 acc = {0.f, 0.f, 0.f, 0.f, 0.f, 0.f, 0.f, 0.f,
                  0.f, 0.f, 0.f, 0.f, 0.f, 0.f, 0.f, 0.f};
#pragma unroll
    for (int kk = 0; kk < 8; ++kk) {
      bf16x8 A = *(const bf16x8*)&sX[(mt * 32 + l31) * T_STR + kk * 16 + lhalf * 8];
      acc = __builtin_amdgcn_mfma_f32_32x32x16_bf16(A, BW[kk], acc, 0, 0, 0);
    }
#pragma unroll
    for (int r = 0; r < 16; ++r) {
      const int rowm = mt * 32 + (r & 3) + 8 * (r >> 2) + 4 * lhalf;
      hbf[(size_t)(rbase + rowm) * OUT_CH + nbase] = f2bf(acc[r] + blv);
    }
  }
}

// ---------------------------------------------------------------------------
// counting sort of edges by dst (row)
// ---------------------------------------------------------------------------
__global__ void hist_kernel(const int* __restrict__ rowI, int* __restrict__ count) {
  int e = blockIdx.x * 256 + threadIdx.x;
  if (e < N_EDGES) atomicAdd(&count[rowI[e]], 1);
}

__global__ __launch_bounds__(1024) void scan_kernel(const int* __restrict__ count,
                                                    int* __restrict__ cursor) {
  __shared__ int sSum[1024];
  const int t = threadIdx.x;
  const int per = (N_NODES + 1023) / 1024;  // 40
  const int base = t * per;
  int s = 0;
  for (int i = 0; i < per; ++i) {
    int idx = base + i;
    if (idx < N_NODES) s += count[idx];
  }
  sSum[t] = s;
  __syncthreads();
  for (int off = 1; off < 1024; off <<= 1) {
    int v = (t >= off) ? sSum[t - off] : 0;
    __syncthreads();
    sSum[t] += v;
    __syncthreads();
  }
  int run = (t == 0) ? 0 : sSum[t - 1];
  for (int i = 0; i < per; ++i) {
    int idx = base + i;
    if (idx < N_NODES) {
      cursor[idx] = run;
      run += count[idx];
    }
  }
}

__global__ void scatter_kernel(const int* __restrict__ rowI, int* __restrict__ cursor,
                               int* __restrict__ perm) {
  int e = blockIdx.x * 256 + threadIdx.x;
  if (e < N_EDGES) {
    int pos = atomicAdd(&cursor[rowI[e]], 1);
    perm[pos] = e;
  }
}

// ---------------------------------------------------------------------------
// fused edge kernel over dst-sorted edges
// ---------------------------------------------------------------------------
__global__ __launch_bounds__(256, 3) void cfconv_edge_kernel(
    const int* __restrict__ eidx, const float* __restrict__ rbf,
    const float* __restrict__ W1, const float* __restrict__ b1,
    const float* __restrict__ W2, const float* __restrict__ b2,
    const unsigned short* __restrict__ hbf, const int* __restrict__ perm,
    float* __restrict__ out) {
  __shared__ __align__(16) char pool[POOL_BYTES];  // 43008 B, aliased
  __shared__ int sDst[TILE_M], sSrc[TILE_M], sLdst[TILE_M], sGdst[TILE_M];
  __shared__ int sNdist;

  unsigned short* sT = (unsigned short*)pool;               // [64][T_STR] ushort
  float* sAccF = (float*)pool;                              // [64][ACC_STR] float (alias)
  unsigned short* sRbf = (unsigned short*)(pool + TILE_M * ACC_STR * 4);

  const int t = threadIdx.x;
  const int lane = t & 63;
  const int l31 = lane & 31;
  const int lhalf = lane >> 5;
  const int wv = t >> 6;
  const int nbase = wv * 32 + l31;

  // ---- init: stage W1^T -> B1 frags, then W2^T -> B2 frags (pool reused) ----
  {
    unsigned short* sW1T = (unsigned short*)pool;
    const int k = t >> 2;
    const int c0 = (t & 3) * 32;
#pragma unroll
    for (int i = 0; i < 8; ++i) {
      float4 v = *(const float4*)(W1 + k * OUT_CH + c0 + 4 * i);
      sW1T[(c0 + 4 * i + 0) * W1_STR + k] = f2bf(v.x);
      sW1T[(c0 + 4 * i + 1) * W1_STR + k] = f2bf(v.y);
      sW1T[(c0 + 4 * i + 2) * W1_STR + k] = f2bf(v.z);
      sW1T[(c0 + 4 * i + 3) * W1_STR + k] = f2bf(v.w);
    }
  }
  __syncthreads();
  bf16x8 B1[4];
  {
    const unsigned short* sW1T = (const unsigned short*)pool;
#pragma unroll
    for (int kk = 0; kk < 4; ++kk)
      B1[kk] = *(const bf16x8*)&sW1T[nbase * W1_STR + kk * 16 + lhalf * 8];
  }
  __syncthreads();
  {
    unsigned short* sW2T = (unsigned short*)pool;
    const int k2 = t >> 1;
    const int d0 = (t & 1) * 64;
#pragma unroll
    for (int i = 0; i < 16; ++i) {
      float4 v = *(const float4*)(W2 + k2 * OUT_CH + d0 + 4 * i);
      sW2T[(d0 + 4 * i + 0) * W2_STR + k2] = f2bf(v.x);
      sW2T[(d0 + 4 * i + 1) * W2_STR + k2] = f2bf(v.y);
      sW2T[(d0 + 4 * i + 2) * W2_STR + k2] = f2bf(v.z);
      sW2T[(d0 + 4 * i + 3) * W2_STR + k2] = f2bf(v.w);
    }
  }
  __syncthreads();
  bf16x8 B2[8];
  {
    const unsigned short* sW2T = (const unsigned short*)pool;
#pragma unroll
    for (int kk = 0; kk < 8; ++kk)
      B2[kk] = *(const bf16x8*)&sW2T[nbase * W2_STR + kk * 16 + lhalf * 8];
  }
  const float b1v = b1[nbase];
  const float b2v = b2[nbase];

  const int* rowI = eidx;
  const int* colI = eidx + N_EDGES;

  for (int tile = blockIdx.x; tile < NTILES; tile += gridDim.x) {
    const int ebase = tile * TILE_M;
    __syncthreads();  // (a) prev flush / B2 frag reads done before pool rewrite

    // ---- stage rbf (gathered via perm) + sorted dst/src ----
    {
      const int m = t >> 2;
      const int pe = perm[ebase + m];  // 4 lanes same addr -> broadcast
      const int kq = (t & 3) * 16;
      const float* src = rbf + (size_t)pe * NUM_RBF + kq;
#pragma unroll
      for (int i = 0; i < 4; ++i) {
        float4 v = *(const float4*)(src + 4 * i);
        ushort4 p;
        p.x = f2bf(v.x); p.y = f2bf(v.y); p.z = f2bf(v.z); p.w = f2bf(v.w);
        *(ushort4*)&sRbf[m * RBF_STR + kq + 4 * i] = p;
      }
      if (t < TILE_M) {
        const int pe2 = perm[ebase + t];
        sDst[t] = rowI[pe2];
        sSrc[t] = colI[pe2];
      }
    }
    __syncthreads();  // (b)

    // ---- GEMM1: sT = bf16(relu(rbf @ W1 + b1)) ----
#pragma unroll
    for (int mt = 0; mt < 2; ++mt) {
      f32x16 acc = {0.f, 0.f, 0.f, 0.f, 0.f, 0.f, 0.f, 0.f,
                    0.f, 0.f, 0.f, 0.f, 0.f, 0.f, 0.f, 0.f};
#pragma unroll
      for (int kk = 0; kk < 4; ++kk) {
        bf16x8 A = *(const bf16x8*)&sRbf[(mt * 32 + l31) * RBF_STR + kk * 16 + lhalf * 8];
        acc = __builtin_amdgcn_mfma_f32_32x32x16_bf16(A, B1[kk], acc, 0, 0, 0);
      }
#pragma unroll
      for (int r = 0; r < 16; ++r) {
        const int rowm = (r & 3) + 8 * (r >> 2) + 4 * lhalf;
        float v = acc[r] + b1v;
        v = v > 0.f ? v : 0.f;
        sT[(mt * 32 + rowm) * T_STR + nbase] = f2bf(v);
      }
    }
    __syncthreads();  // (c)

    // ---- prefetch gathered h values (hide latency under GEMM2) ----
    float hv[2][16];
#pragma unroll
    for (int mt = 0; mt < 2; ++mt)
#pragma unroll
      for (int r = 0; r < 16; ++r) {
        const int rowm = mt * 32 + (r & 3) + 8 * (r >> 2) + 4 * lhalf;
        hv[mt][r] = bf2f(hbf[(size_t)sSrc[rowm] * OUT_CH + nbase]);
      }

    // ---- GEMM2 (acc in regs) ----
    f32x16 acc2[2];
#pragma unroll
    for (int mt = 0; mt < 2; ++mt) {
      f32x16 acc = {0.f, 0.f, 0.f, 0.f, 0.f, 0.f, 0.f, 0.f,
                    0.f, 0.f, 0.f, 0.f, 0.f, 0.f, 0.f, 0.f};
#pragma unroll
      for (int kk = 0; kk < 8; ++kk) {
        bf16x8 A = *(const bf16x8*)&sT[(mt * 32 + l31) * T_STR + kk * 16 + lhalf * 8];
        acc = __builtin_amdgcn_mfma_f32_32x32x16_bf16(A, B2[kk], acc, 0, 0, 0);
      }
      acc2[mt] = acc;
    }

    // ---- dst run-length scan (wave 0; sorted => non-decreasing) ----
    if (t < 64) {
      const int d = sDst[t];
      const int dp = __shfl_up(d, 1, 64);
      const int f = (t == 0 || d != dp) ? 1 : 0;
      int sc = f;
#pragma unroll
      for (int off = 1; off < 64; off <<= 1) {
        int v = __shfl_up(sc, off, 64);
        if (t >= off) sc += v;
      }
      sLdst[t] = sc - 1;
      if (f) sGdst[sc - 1] = d;
      if (t == 63) sNdist = sc;
    }
    __syncthreads();  // (d) sT reads done + scan done -> pool becomes sAccF

    const int nd = sNdist;
    for (int i = t; i < nd * ACC_STR; i += 256) sAccF[i] = 0.f;
    __syncthreads();  // (e)

    // ---- accumulate messages into per-run LDS rows ----
#pragma unroll
    for (int mt = 0; mt < 2; ++mt)
#pragma unroll
      for (int r = 0; r < 16; ++r) {
        const int rowm = mt * 32 + (r & 3) + 8 * (r >> 2) + 4 * lhalf;
        const float wval = acc2[mt][r] + b2v;
        atomicAdd(&sAccF[sLdst[rowm] * ACC_STR + nbase], hv[mt][r] * wval);
      }
    __syncthreads();  // (f)

    // ---- flush runs: one global atomic per (distinct dst, channel) ----
    for (int i = t; i < nd * OUT_CH; i += 256) {
      const int d = i >> 7;
      const int c = i & 127;
      atomicAdd(&out[(size_t)sGdst[d] * OUT_CH + c], sAccF[d * ACC_STR + c]);
    }
  }
}

extern "C" void kernel_launch(void* const* d_in, const int* in_sizes, int n_in,
                              void* d_out, int out_size, void* d_ws, size_t ws_size,
                              hipStream_t stream) {
  const float* x    = (const float*)d_in[0];
  const int*   eidx = (const int*)d_in[1];
  const float* rbf  = (const float*)d_in[2];
  const float* W1   = (const float*)d_in[3];
  const float* b1   = (const float*)d_in[4];
  const float* W2   = (const float*)d_in[5];
  const float* b2   = (const float*)d_in[6];
  const float* Wl   = (const float*)d_in[7];
  const float* bl   = (const float*)d_in[8];
  float* out = (float*)d_out;

  char* ws = (char*)d_ws;
  unsigned short* hbf = (unsigned short*)ws;          // 10,240,000 B
  int* perm   = (int*)(ws + 10240000);                //  2,560,000 B
  int* count  = (int*)(ws + 12800000);                //    160,000 B
  int* cursor = (int*)(ws + 12960000);                //    160,000 B

  hipMemsetAsync(out, 0, sizeof(float) * N_NODES * OUT_CH, stream);
  hipMemsetAsync(count, 0, sizeof(int) * N_NODES, stream);
  node_linear_mfma<<<N_NODES / TILE_M, 256, 0, stream>>>(x, Wl, bl, hbf);
  hist_kernel<<<(N_EDGES + 255) / 256, 256, 0, stream>>>(eidx, count);
  scan_kernel<<<1, 1024, 0, stream>>>(count, cursor);
  scatter_kernel<<<(N_EDGES + 255) / 256, 256, 0, stream>>>(eidx, cursor, perm);
  cfconv_edge_kernel<<<768, 256, 0, stream>>>(eidx, rbf, W1, b1, W2, b2, hbf, perm, out);
}